// Round 1
// baseline (2130.856 us; speedup 1.0000x reference)
//
#include <hip/hip_runtime.h>
#include <math.h>

#define L 1024
#define BATCH 32
#define TS 64
#define PAD 65
#define NT 16        // tiles per dim
#define NPAIRS 136   // NT*(NT+1)/2
#define STEPS 20

__device__ __forceinline__ float4 ld4(const float* p) { return *(const float4*)p; }

// pbuf layout: [0..19] a_t = alpha*lr_alpha^t, [20..39] belt*lr_belt^t, [40] s, [41] w
__global__ void params_kernel(float* pbuf, const float* s, const float* w,
                              const float* alpha, const float* belt,
                              const float* lra, const float* lrb) {
  int t = threadIdx.x;
  if (t < STEPS) {
    pbuf[t]         = alpha[0] * powf(lra[0], (float)t);
    pbuf[STEPS + t] = belt[0]  * powf(lrb[0], (float)t);
  }
  if (t == 0) { pbuf[2*STEPS] = s[0]; pbuf[2*STEPS + 1] = w[0]; }
}

// Reduce per-tile row partials -> rowsum; update Lm (dual ascent from PREVIOUS step's
// new A rowsums); emit c = Lm * sign(rowsum - 1).
__global__ __launch_bounds__(256)
void c_kernel(const float* __restrict__ rs_part, float* __restrict__ Lm,
              float* __restrict__ cvec, const float* __restrict__ pbuf, int t) {
  int idx = blockIdx.x * 256 + threadIdx.x;   // < BATCH*L
  int b = idx >> 10;
  int i = idx & (L - 1);
  const float* base = rs_part + ((size_t)b * NT) * L + i;
  float rs = 0.f;
  #pragma unroll
  for (int tj = 0; tj < NT; ++tj) rs += base[(size_t)tj * L];
  float row = rs - 1.0f;
  float rl  = fmaxf(row, 0.f);
  float lm;
  if (t == 0) lm = pbuf[2*STEPS + 1] * rl;               // Lm init: w*relu(row0)
  else        lm = Lm[idx] + pbuf[STEPS + t - 1] * rl;   // Lm += belt*lr^(t-1)*relu(row)
  Lm[idx] = lm;
  float sg = (row > 0.f) ? 1.f : ((row < 0.f) ? -1.f : 0.f);
  cvec[idx] = lm * sg;
}

// MODE: 0 = init (Ahat=scores, rowsums of T_A(scores))
//       1 = one optimization step (update Ahat, emit rowsum partials of new A)
//       2 = final (in-place Ahat -> A in d_out)
template<int MODE>
__global__ __launch_bounds__(256)
void tile_kernel(const float* __restrict__ scores, const float* __restrict__ Mm,
                 const float* __restrict__ rho, float* __restrict__ Ahat,
                 const float* __restrict__ cvec, float* __restrict__ rs_part,
                 const float* __restrict__ pbuf, int t)
{
  __shared__ float bufA[TS * PAD];   // staged "ji" tile, later Hn_ji
  __shared__ float bufB[TS * PAD];   // symmetric gradient g (STEP only)
  __shared__ float bufC[TS * PAD];   // Hn_ij
  __shared__ float cI[TS], cJ[TS];

  const int b = blockIdx.y;
  int p = blockIdx.x;
  int bi = 0;
  while (p >= (NT - bi)) { p -= (NT - bi); ++bi; }
  const int bj = bi + p;
  const bool diag = (bi == bj);
  const int ibase = bi * TS, jbase = bj * TS;
  const int tid = threadIdx.x;
  const int cg = tid & 15;    // column group of 4 floats
  const int rr = tid >> 4;    // row within 16-row stripe
  const int c4 = cg * 4;
  const size_t bb = (size_t)b * L * L;

  // ---- phase 1: stage tile-ji (scores for init/step, Ahat for final) ----
  const float* stageSrc = (MODE == 2) ? (const float*)Ahat : scores;
  #pragma unroll
  for (int it = 0; it < 4; ++it) {
    int row = it * 16 + rr;
    float4 v = ld4(stageSrc + bb + (size_t)(jbase + row) * L + ibase + c4);
    float* d = &bufA[row * PAD + c4];
    d[0] = v.x; d[1] = v.y; d[2] = v.z; d[3] = v.w;
  }
  if (MODE == 1) {
    if (tid < TS)            cI[tid]       = cvec[b * L + ibase + tid];
    else if (tid < 2 * TS)   cJ[tid - TS]  = cvec[b * L + jbase + (tid - TS)];
  }
  __syncthreads();

  float a_t = 0.f, s_val = 0.f;
  if (MODE == 1) { a_t = pbuf[t]; s_val = pbuf[2*STEPS]; }

  float hnR[4][4];   // new Ahat (tile-ij), kept for phase 4
  float mR[4][4];    // M (tile-ij), kept for phase 4

  // ---- phase 2: tile-ij update ----
  #pragma unroll
  for (int it = 0; it < 4; ++it) {
    int ii = it * 16 + rr;
    size_t off = bb + (size_t)(ibase + ii) * L + jbase + c4;
    float4 m4 = ld4(Mm + off);
    mR[it][0]=m4.x; mR[it][1]=m4.y; mR[it][2]=m4.z; mR[it][3]=m4.w;
    float hn[4];
    if (MODE == 0) {
      float4 s4 = ld4(scores + off);
      hn[0]=s4.x; hn[1]=s4.y; hn[2]=s4.z; hn[3]=s4.w;
      *(float4*)(Ahat + off) = s4;               // Ahat = scores
    } else if (MODE == 1) {
      float4 s4 = ld4(scores + off);
      float4 h4 = ld4(Ahat + off);
      float4 r4 = ld4(rho + (size_t)(ibase + ii) * L + jbase + c4);
      float sc[4] = {s4.x,s4.y,s4.z,s4.w};
      float h [4] = {h4.x,h4.y,h4.z,h4.w};
      float rh[4] = {r4.x,r4.y,r4.z,r4.w};
      float ci = cI[ii];
      #pragma unroll
      for (int k = 0; k < 4; ++k) {
        float scT = bufA[(c4 + k) * PAD + ii];                       // scores[j,i]
        float g = 0.5f * (sc[k] + scT) - s_val - ci - cJ[c4 + k];    // (G+G^T)[i,j]
        float x = fmaf(a_t * h[k] * mR[it][k], g, h[k]);             // Ahat += a_t*Ahat*M*g
        x = fabsf(x) - rh[k] * a_t;                                  // soft-threshold
        x = fminf(fmaxf(x, 0.f), 1.f);                               // relu + clip@1
        hn[k] = x;
        bufB[ii * PAD + c4 + k] = g;                                 // share g (symmetric)
      }
      float4 o; o.x=hn[0]; o.y=hn[1]; o.z=hn[2]; o.w=hn[3];
      *(float4*)(Ahat + off) = o;
    } else { // FINAL: just load current Ahat_ij
      float4 h4 = ld4(Ahat + off);
      hn[0]=h4.x; hn[1]=h4.y; hn[2]=h4.z; hn[3]=h4.w;
    }
    #pragma unroll
    for (int k = 0; k < 4; ++k) {
      hnR[it][k] = hn[k];
      bufC[ii * PAD + c4 + k] = hn[k];
    }
  }
  __syncthreads();

  // ---- phase 3: tile-ji (skipped on diagonal) ----
  if (!diag) {
    #pragma unroll
    for (int it = 0; it < 4; ++it) {
      int jj = it * 16 + rr;
      size_t off = bb + (size_t)(jbase + jj) * L + ibase + c4;
      float4 m4 = ld4(Mm + off);
      float m[4] = {m4.x,m4.y,m4.z,m4.w};
      float hn[4];
      if (MODE == 0) {
        #pragma unroll
        for (int k = 0; k < 4; ++k) hn[k] = bufA[jj * PAD + c4 + k]; // scores_ji
        float4 o; o.x=hn[0]; o.y=hn[1]; o.z=hn[2]; o.w=hn[3];
        *(float4*)(Ahat + off) = o;                                   // Ahat_ji = scores_ji
      } else if (MODE == 1) {
        float4 h4 = ld4(Ahat + off);
        float4 r4 = ld4(rho + (size_t)(jbase + jj) * L + ibase + c4);
        float h [4] = {h4.x,h4.y,h4.z,h4.w};
        float rh[4] = {r4.x,r4.y,r4.z,r4.w};
        #pragma unroll
        for (int k = 0; k < 4; ++k) {
          float g = bufB[(c4 + k) * PAD + jj];                        // g[j,i] = g[i,j]
          float x = fmaf(a_t * h[k] * m[k], g, h[k]);
          x = fabsf(x) - rh[k] * a_t;
          x = fminf(fmaxf(x, 0.f), 1.f);
          hn[k] = x;
          bufA[jj * PAD + c4 + k] = x;                                // Hn_ji for phase 4
        }
        float4 o; o.x=hn[0]; o.y=hn[1]; o.z=hn[2]; o.w=hn[3];
        *(float4*)(Ahat + off) = o;
      } else { // FINAL: A_ji = 0.5*(Hji + Hij^T)*M_ji
        float av[4];
        #pragma unroll
        for (int k = 0; k < 4; ++k) {
          float hji  = bufA[jj * PAD + c4 + k];
          float hijT = bufC[(c4 + k) * PAD + jj];
          av[k] = 0.5f * (hji + hijT) * m[k];
        }
        float4 o; o.x=av[0]; o.y=av[1]; o.z=av[2]; o.w=av[3];
        *(float4*)(Ahat + off) = o;
      }
      if (MODE <= 1) {
        // rowsum partial for row (jbase+jj), column block bi
        float part = 0.f;
        #pragma unroll
        for (int k = 0; k < 4; ++k) {
          float hijT = bufC[(c4 + k) * PAD + jj];
          part += 0.5f * (hn[k] + hijT) * m[k];
        }
        part += __shfl_xor(part, 1);
        part += __shfl_xor(part, 2);
        part += __shfl_xor(part, 4);
        part += __shfl_xor(part, 8);
        if ((tid & 15) == 0)
          rs_part[((size_t)b * NT + bi) * L + jbase + jj] = part;
      }
    }
    __syncthreads();
  }

  // ---- phase 4: tile-ij rows (rowsum partials, or final A write) ----
  const float* hsrc = diag ? bufC : bufA;
  #pragma unroll
  for (int it = 0; it < 4; ++it) {
    int ii = it * 16 + rr;
    if (MODE <= 1) {
      float part = 0.f;
      #pragma unroll
      for (int k = 0; k < 4; ++k) {
        float hT = hsrc[(c4 + k) * PAD + ii];         // Hn[j,i]
        part += 0.5f * (hnR[it][k] + hT) * mR[it][k];
      }
      part += __shfl_xor(part, 1);
      part += __shfl_xor(part, 2);
      part += __shfl_xor(part, 4);
      part += __shfl_xor(part, 8);
      if ((tid & 15) == 0)
        rs_part[((size_t)b * NT + bj) * L + ibase + ii] = part;
    } else {
      float av[4];
      #pragma unroll
      for (int k = 0; k < 4; ++k) {
        float hT = hsrc[(c4 + k) * PAD + ii];
        av[k] = 0.5f * (hnR[it][k] + hT) * mR[it][k];
      }
      size_t off = bb + (size_t)(ibase + ii) * L + jbase + c4;
      float4 o; o.x=av[0]; o.y=av[1]; o.z=av[2]; o.w=av[3];
      *(float4*)(Ahat + off) = o;
    }
  }
}

extern "C" void kernel_launch(void* const* d_in, const int* in_sizes, int n_in,
                              void* d_out, int out_size, void* d_ws, size_t ws_size,
                              hipStream_t stream) {
  const float* scores = (const float*)d_in[0];
  const float* Mm     = (const float*)d_in[1];
  const float* rho    = (const float*)d_in[2];
  const float* s      = (const float*)d_in[3];
  const float* w      = (const float*)d_in[4];
  const float* alpha  = (const float*)d_in[5];
  const float* belt   = (const float*)d_in[6];
  const float* lra    = (const float*)d_in[7];
  const float* lrb    = (const float*)d_in[8];
  float* Ahat = (float*)d_out;

  char* ws = (char*)d_ws;
  float* rs_part = (float*)ws;                                         // B*NT*L
  float* Lm      = (float*)(ws + (size_t)BATCH*NT*L*4);                // B*L
  float* cvec    = (float*)(ws + (size_t)BATCH*NT*L*4 + (size_t)BATCH*L*4);
  float* pbuf    = (float*)(ws + (size_t)BATCH*NT*L*4 + 2*(size_t)BATCH*L*4);

  params_kernel<<<1, 64, 0, stream>>>(pbuf, s, w, alpha, belt, lra, lrb);

  dim3 grid(NPAIRS, BATCH);
  tile_kernel<0><<<grid, 256, 0, stream>>>(scores, Mm, rho, Ahat, cvec, rs_part, pbuf, 0);
  for (int tt = 0; tt < STEPS; ++tt) {
    c_kernel<<<BATCH*L/256, 256, 0, stream>>>(rs_part, Lm, cvec, pbuf, tt);
    tile_kernel<1><<<grid, 256, 0, stream>>>(scores, Mm, rho, Ahat, cvec, rs_part, pbuf, tt);
  }
  tile_kernel<2><<<grid, 256, 0, stream>>>(scores, Mm, rho, Ahat, cvec, rs_part, pbuf, 0);
}

// Round 2
// 1754.559 us; speedup vs baseline: 1.2145x; 1.2145x over previous
//
#include <hip/hip_runtime.h>
#include <math.h>

#define L 1024
#define BATCH 32
#define TS 64
#define PAD 65
#define NT 16
#define NPAIRS 136
#define STEPS 20

struct __align__(8) us4 { unsigned short x, y, z, w; };

__device__ __forceinline__ float4 ld4(const float* p){ return *(const float4*)p; }
__device__ __forceinline__ unsigned short f2bf(float x){
  unsigned int u = __float_as_uint(x);
  u += 0x7fffu + ((u >> 16) & 1u);
  return (unsigned short)(u >> 16);
}
__device__ __forceinline__ float bf2f(unsigned short b){
  return __uint_as_float(((unsigned int)b) << 16);
}
__device__ __forceinline__ float red16(float v){
  v += __shfl_xor(v, 1); v += __shfl_xor(v, 2);
  v += __shfl_xor(v, 4); v += __shfl_xor(v, 8);
  return v;
}
__device__ __forceinline__ void decode_pair(int p, int& bi, int& bj){
  bi = 0;
  while (p >= NT - bi){ p -= NT - bi; ++bi; }
  bj = bi + p;
}

// pbuf: [0..19] a_t, [20..39] belt*lr_belt^t, [40] s, [41] w
__global__ void params_kernel(float* pbuf, const float* s, const float* w,
                              const float* alpha, const float* belt,
                              const float* lra, const float* lrb) {
  int t = threadIdx.x;
  if (t < STEPS) {
    pbuf[t]         = alpha[0] * powf(lra[0], (float)t);
    pbuf[STEPS + t] = belt[0]  * powf(lrb[0], (float)t);
  }
  if (t == 0) { pbuf[2*STEPS] = s[0]; pbuf[2*STEPS + 1] = w[0]; }
}

// prep: Ahat = scores; S_bar = 0.5(sc+scT)-s (bf16, if SB); rowsum partials of A0
template<bool SB>
__global__ __launch_bounds__(256, 4)
void prep_kernel(const float* __restrict__ scores, const float* __restrict__ Mm,
                 float* __restrict__ H, unsigned short* __restrict__ Sb,
                 float* __restrict__ rsOut, const float* __restrict__ pbuf)
{
  __shared__ float buf1[TS*PAD];
  __shared__ float buf2[TS*PAD];
  const int b = blockIdx.y;
  int bi, bj; decode_pair(blockIdx.x, bi, bj);
  const bool diag = (bi == bj);
  const int ibase = bi*TS, jbase = bj*TS;
  const int tid = threadIdx.x, cg = tid & 15, rr = tid >> 4, c4 = cg*4;
  const size_t bb = (size_t)b * L * L;
  const float sv = pbuf[2*STEPS];

  #pragma unroll
  for (int it = 0; it < 4; ++it){
    int row = it*16 + rr;
    size_t off = bb + (size_t)(jbase+row)*L + ibase + c4;
    float4 v = ld4(scores + off);
    float* d = &buf1[row*PAD + c4];
    d[0]=v.x; d[1]=v.y; d[2]=v.z; d[3]=v.w;
    *(float4*)(H + off) = v;                       // Ahat_ji = scores_ji
  }
  __syncthreads();

  #pragma unroll
  for (int it = 0; it < 4; ++it){
    int ii = it*16 + rr;
    size_t off = bb + (size_t)(ibase+ii)*L + jbase + c4;
    float4 s4 = ld4(scores + off);
    float4 m4 = ld4(Mm + off);
    float sc[4] = {s4.x,s4.y,s4.z,s4.w};
    float m [4] = {m4.x,m4.y,m4.z,m4.w};
    float part = 0.f;
    unsigned short q[4];
    #pragma unroll
    for (int k = 0; k < 4; ++k){
      float scT = buf1[(c4+k)*PAD + ii];
      float sbv = 0.5f*(sc[k] + scT) - sv;
      buf2[ii*PAD + c4 + k] = sbv;
      part += (sbv + sv) * m[k];                   // A0_ij = 0.5(sc+scT)*M
      q[k] = f2bf(sbv);
    }
    if (!diag) *(float4*)(H + off) = s4;           // Ahat_ij = scores_ij
    if constexpr (SB){ us4 o = {q[0],q[1],q[2],q[3]}; *(us4*)(Sb + off) = o; }
    part = red16(part);
    if (cg == 0) rsOut[((size_t)b*NT + bj)*L + ibase + ii] = part;
  }
  __syncthreads();

  if (!diag){
    #pragma unroll
    for (int it = 0; it < 4; ++it){
      int jj = it*16 + rr;
      size_t off = bb + (size_t)(jbase+jj)*L + ibase + c4;
      float4 m4 = ld4(Mm + off);
      float m[4] = {m4.x,m4.y,m4.z,m4.w};
      float part = 0.f;
      unsigned short q[4];
      #pragma unroll
      for (int k = 0; k < 4; ++k){
        float sbT = buf2[(c4+k)*PAD + jj];         // S_bar is symmetric
        part += (sbT + sv) * m[k];
        q[k] = f2bf(sbT);
      }
      if constexpr (SB){ us4 o = {q[0],q[1],q[2],q[3]}; *(us4*)(Sb + off) = o; }
      part = red16(part);
      if (cg == 0) rsOut[((size_t)b*NT + bi)*L + jbase + jj] = part;
    }
  }
}

// one optimization step; Lm/c computed in-kernel (rs_part + Lm double-buffered)
template<bool SB>
__global__ __launch_bounds__(256, 4)
void step_kernel(const float* __restrict__ scores, const unsigned short* __restrict__ Sb,
                 const float* __restrict__ Mm, const float* __restrict__ rho,
                 float* __restrict__ H,
                 const float* __restrict__ rsIn, float* __restrict__ rsOut,
                 const float* __restrict__ LmIn, float* __restrict__ LmOut,
                 const float* __restrict__ pbuf, const int t)
{
  __shared__ float bufP[TS*PAD];                 // Hn_ij
  __shared__ float bufQ[TS*PAD];                 // staged sc_ji (!SB, pre-A) / Hn_ji (B)
  __shared__ float bufG[SB ? 4 : TS*PAD];        // shared g (!SB only)
  __shared__ float cbuf[2*TS];

  const int b = blockIdx.y;
  int bi, bj; decode_pair(blockIdx.x, bi, bj);
  const bool diag = (bi == bj);
  const int ibase = bi*TS, jbase = bj*TS;
  const int tid = threadIdx.x, cg = tid & 15, rr = tid >> 4, c4 = cg*4;
  const size_t bb = (size_t)b * L * L;
  const float a_t = pbuf[t];

  // ---- c phase: every block recomputes rowsum/Lm/c for its 128 rows ----
  if (tid < 128){
    const int half = tid >> 6, lane = tid & 63;
    const int rowbase = half ? jbase : ibase;
    const float* rp = rsIn + (size_t)b*NT*L + rowbase + lane;
    float rs = 0.f;
    #pragma unroll
    for (int pq = 0; pq < NT; ++pq) rs += rp[(size_t)pq * L];
    const float rowm = rs - 1.0f;
    const float rl = fmaxf(rowm, 0.f);
    float lm;
    if (t == 0) lm = pbuf[2*STEPS+1] * rl;
    else        lm = LmIn[(size_t)b*L + rowbase + lane] + pbuf[STEPS + t - 1] * rl;
    const float sg = (rowm > 0.f) ? 1.f : ((rowm < 0.f) ? -1.f : 0.f);
    cbuf[tid] = lm * sg;
    if (half == 0) LmOut[(size_t)b*L + rowbase + lane] = lm;   // identical dup writes ok
  }
  if constexpr (!SB){
    #pragma unroll
    for (int it = 0; it < 4; ++it){
      int row = it*16 + rr;
      float4 v = ld4(scores + bb + (size_t)(jbase+row)*L + ibase + c4);
      float* d = &bufQ[row*PAD + c4];
      d[0]=v.x; d[1]=v.y; d[2]=v.z; d[3]=v.w;
    }
  }
  __syncthreads();

  float mR[4][4], part1[4];
  const float sv = SB ? 0.f : pbuf[2*STEPS];

  // ---- phase A: tile-ij update ----
  #pragma unroll
  for (int it = 0; it < 4; ++it){
    const int ii = it*16 + rr;
    const size_t off = bb + (size_t)(ibase+ii)*L + jbase + c4;
    float4 h4 = ld4(H + off);
    float4 m4 = ld4(Mm + off);
    float4 r4 = ld4(rho + (size_t)(ibase+ii)*L + jbase + c4);
    float h[4] = {h4.x,h4.y,h4.z,h4.w};
    float m[4] = {m4.x,m4.y,m4.z,m4.w};
    float rh[4]= {r4.x,r4.y,r4.z,r4.w};
    float sb[4];
    if constexpr (SB){
      us4 s4 = *(const us4*)(Sb + off);
      sb[0]=bf2f(s4.x); sb[1]=bf2f(s4.y); sb[2]=bf2f(s4.z); sb[3]=bf2f(s4.w);
    } else {
      float4 s4 = ld4(scores + off);
      float scv[4] = {s4.x,s4.y,s4.z,s4.w};
      #pragma unroll
      for (int k = 0; k < 4; ++k)
        sb[k] = 0.5f*(scv[k] + bufQ[(c4+k)*PAD + ii]) - sv;
    }
    const float ci = cbuf[ii];
    float p1 = 0.f, hn[4];
    #pragma unroll
    for (int k = 0; k < 4; ++k){
      const float g = sb[k] - ci - cbuf[TS + c4 + k];
      float x = fmaf(a_t * h[k] * m[k], g, h[k]);
      x = fabsf(x) - rh[k]*a_t;
      x = fminf(fmaxf(x, 0.f), 1.f);
      hn[k] = x;
      bufP[ii*PAD + c4 + k] = x;
      if constexpr (!SB) bufG[ii*PAD + c4 + k] = g;
      p1 += 0.5f * x * m[k];
      mR[it][k] = m[k];
    }
    part1[it] = p1;
    float4 o; o.x=hn[0]; o.y=hn[1]; o.z=hn[2]; o.w=hn[3];
    *(float4*)(H + off) = o;
  }
  __syncthreads();

  // ---- phase B: tile-ji update + rows-j partials ----
  if (!diag){
    #pragma unroll
    for (int it = 0; it < 4; ++it){
      const int jj = it*16 + rr;
      const size_t off = bb + (size_t)(jbase+jj)*L + ibase + c4;
      float4 h4 = ld4(H + off);
      float4 m4 = ld4(Mm + off);
      float4 r4 = ld4(rho + (size_t)(jbase+jj)*L + ibase + c4);
      float h[4] = {h4.x,h4.y,h4.z,h4.w};
      float m[4] = {m4.x,m4.y,m4.z,m4.w};
      float rh[4]= {r4.x,r4.y,r4.z,r4.w};
      float g[4];
      if constexpr (SB){
        us4 s4 = *(const us4*)(Sb + off);
        g[0] = bf2f(s4.x) - cbuf[TS + jj] - cbuf[c4+0];
        g[1] = bf2f(s4.y) - cbuf[TS + jj] - cbuf[c4+1];
        g[2] = bf2f(s4.z) - cbuf[TS + jj] - cbuf[c4+2];
        g[3] = bf2f(s4.w) - cbuf[TS + jj] - cbuf[c4+3];
      } else {
        #pragma unroll
        for (int k = 0; k < 4; ++k) g[k] = bufG[(c4+k)*PAD + jj];  // g symmetric
      }
      float part = 0.f, hn[4];
      #pragma unroll
      for (int k = 0; k < 4; ++k){
        float x = fmaf(a_t * h[k] * m[k], g[k], h[k]);
        x = fabsf(x) - rh[k]*a_t;
        x = fminf(fmaxf(x, 0.f), 1.f);
        hn[k] = x;
        part += 0.5f * (x + bufP[(c4+k)*PAD + jj]) * m[k];
        bufQ[jj*PAD + c4 + k] = x;
      }
      float4 o; o.x=hn[0]; o.y=hn[1]; o.z=hn[2]; o.w=hn[3];
      *(float4*)(H + off) = o;
      part = red16(part);
      if (cg == 0) rsOut[((size_t)b*NT + bi)*L + jbase + jj] = part;
    }
  }
  __syncthreads();

  // ---- phase C: rows-i partials ----
  const float* hs = diag ? bufP : bufQ;
  #pragma unroll
  for (int it = 0; it < 4; ++it){
    const int ii = it*16 + rr;
    float part = part1[it];
    #pragma unroll
    for (int k = 0; k < 4; ++k)
      part += 0.5f * hs[(c4+k)*PAD + ii] * mR[it][k];
    part = red16(part);
    if (cg == 0) rsOut[((size_t)b*NT + bj)*L + ibase + ii] = part;
  }
}

// final: A = 0.5(H + H^T)*M, in place
__global__ __launch_bounds__(256, 4)
void final_kernel(const float* __restrict__ Mm, float* __restrict__ H)
{
  __shared__ float buf1[TS*PAD];   // H_ji
  __shared__ float buf2[TS*PAD];   // H_ij (pre-overwrite)
  const int b = blockIdx.y;
  int bi, bj; decode_pair(blockIdx.x, bi, bj);
  const bool diag = (bi == bj);
  const int ibase = bi*TS, jbase = bj*TS;
  const int tid = threadIdx.x, cg = tid & 15, rr = tid >> 4, c4 = cg*4;
  const size_t bb = (size_t)b * L * L;

  #pragma unroll
  for (int it = 0; it < 4; ++it){
    int row = it*16 + rr;
    size_t off = bb + (size_t)(jbase+row)*L + ibase + c4;
    float4 v = ld4(H + off);
    float* d = &buf1[row*PAD + c4];
    d[0]=v.x; d[1]=v.y; d[2]=v.z; d[3]=v.w;
  }
  __syncthreads();

  #pragma unroll
  for (int it = 0; it < 4; ++it){
    int ii = it*16 + rr;
    size_t off = bb + (size_t)(ibase+ii)*L + jbase + c4;
    float4 h4 = ld4(H + off);
    float4 m4 = ld4(Mm + off);
    float h[4] = {h4.x,h4.y,h4.z,h4.w};
    float m[4] = {m4.x,m4.y,m4.z,m4.w};
    float av[4];
    #pragma unroll
    for (int k = 0; k < 4; ++k){
      buf2[ii*PAD + c4 + k] = h[k];
      av[k] = 0.5f*(h[k] + buf1[(c4+k)*PAD + ii]) * m[k];
    }
    float4 o; o.x=av[0]; o.y=av[1]; o.z=av[2]; o.w=av[3];
    *(float4*)(H + off) = o;
  }
  __syncthreads();

  if (!diag){
    #pragma unroll
    for (int it = 0; it < 4; ++it){
      int jj = it*16 + rr;
      size_t off = bb + (size_t)(jbase+jj)*L + ibase + c4;
      float4 m4 = ld4(Mm + off);
      float m[4] = {m4.x,m4.y,m4.z,m4.w};
      float av[4];
      #pragma unroll
      for (int k = 0; k < 4; ++k)
        av[k] = 0.5f*(buf1[jj*PAD + c4 + k] + buf2[(c4+k)*PAD + jj]) * m[k];
      float4 o; o.x=av[0]; o.y=av[1]; o.z=av[2]; o.w=av[3];
      *(float4*)(H + off) = o;
    }
  }
}

extern "C" void kernel_launch(void* const* d_in, const int* in_sizes, int n_in,
                              void* d_out, int out_size, void* d_ws, size_t ws_size,
                              hipStream_t stream) {
  const float* scores = (const float*)d_in[0];
  const float* Mm     = (const float*)d_in[1];
  const float* rho    = (const float*)d_in[2];
  const float* s      = (const float*)d_in[3];
  const float* w      = (const float*)d_in[4];
  const float* alpha  = (const float*)d_in[5];
  const float* belt   = (const float*)d_in[6];
  const float* lra    = (const float*)d_in[7];
  const float* lrb    = (const float*)d_in[8];
  float* H = (float*)d_out;

  const size_t SBB = (size_t)BATCH*L*L*sizeof(unsigned short);  // 64MB
  const size_t RSB = (size_t)BATCH*NT*L*sizeof(float);          // 2MB
  const size_t LMB = (size_t)BATCH*L*sizeof(float);             // 128KB
  char* wp = (char*)d_ws;
  const bool sb = ws_size >= SBB + 2*RSB + 2*LMB + 1024;
  unsigned short* Sb = nullptr;
  size_t off = 0;
  if (sb){ Sb = (unsigned short*)wp; off += SBB; }
  float* rs0  = (float*)(wp + off); off += RSB;
  float* rs1  = (float*)(wp + off); off += RSB;
  float* lm0  = (float*)(wp + off); off += LMB;
  float* lm1  = (float*)(wp + off); off += LMB;
  float* pbuf = (float*)(wp + off);

  params_kernel<<<1, 64, 0, stream>>>(pbuf, s, w, alpha, belt, lra, lrb);

  dim3 grid(NPAIRS, BATCH);
  if (sb) prep_kernel<true ><<<grid, 256, 0, stream>>>(scores, Mm, H, Sb, rs0, pbuf);
  else    prep_kernel<false><<<grid, 256, 0, stream>>>(scores, Mm, H, Sb, rs0, pbuf);

  float* rs[2]  = {rs0, rs1};
  float* lmv[2] = {lm0, lm1};
  for (int t = 0; t < STEPS; ++t){
    float* rin  = rs[t & 1];
    float* rout = rs[(t + 1) & 1];
    const float* lin = lmv[(t + 1) & 1];
    float* lout      = lmv[t & 1];
    if (sb) step_kernel<true ><<<grid, 256, 0, stream>>>(scores, Sb, Mm, rho, H, rin, rout, lin, lout, pbuf, t);
    else    step_kernel<false><<<grid, 256, 0, stream>>>(scores, Sb, Mm, rho, H, rin, rout, lin, lout, pbuf, t);
  }
  final_kernel<<<grid, 256, 0, stream>>>(Mm, H);
}

// Round 3
// 1664.178 us; speedup vs baseline: 1.2804x; 1.0543x over previous
//
#include <hip/hip_runtime.h>
#include <math.h>
#include <type_traits>

#define L 1024
#define BATCH 32
#define TS 64
#define PADF 65
#define PADU 66
#define NT 16
#define NPAIRS 136
#define STEPS 20

struct __align__(8) us4 { unsigned short x, y, z, w; };

__device__ __forceinline__ float4 ld4(const float* p){ return *(const float4*)p; }
__device__ __forceinline__ unsigned short f2bf(float x){
  unsigned int u = __float_as_uint(x);
  u += 0x7fffu + ((u >> 16) & 1u);
  return (unsigned short)(u >> 16);
}
__device__ __forceinline__ float bf2f(unsigned short b){
  return __uint_as_float(((unsigned int)b) << 16);
}
__device__ __forceinline__ float red16(float v){
  v += __shfl_xor(v, 1); v += __shfl_xor(v, 2);
  v += __shfl_xor(v, 4); v += __shfl_xor(v, 8);
  return v;
}
__device__ __forceinline__ void decode_pair(int p, int& bi, int& bj){
  bi = 0;
  while (p >= NT - bi){ p -= NT - bi; ++bi; }
  bj = bi + p;
}

// pbuf: [0..19] a_t, [20..39] belt*lr_belt^t, [40] s, [41] w
__global__ void params_kernel(float* pbuf, const float* s, const float* w,
                              const float* alpha, const float* belt,
                              const float* lra, const float* lrb) {
  int t = threadIdx.x;
  if (t < STEPS) {
    pbuf[t]         = alpha[0] * powf(lra[0], (float)t);
    pbuf[STEPS + t] = belt[0]  * powf(lrb[0], (float)t);
  }
  if (t == 0) { pbuf[2*STEPS] = s[0]; pbuf[2*STEPS + 1] = w[0]; }
}

// prep: S_bar = 0.5(sc+scT)-s -> bf16 Sb (both tiles); optional bf16 Mb;
// rowsum partials of A0 = (S_bar+s)*M. No H write (step0 reads scores).
template<bool PACKM>
__global__ __launch_bounds__(256, 6)
void prep_kernel(const float* __restrict__ scores, const float* __restrict__ Mm,
                 unsigned short* __restrict__ Sb, unsigned short* __restrict__ Mb,
                 float* __restrict__ rsOut, const float* __restrict__ pbuf)
{
  __shared__ float buf1[TS*PADF];            // scores_ji (f32, transposed access)
  __shared__ unsigned short buf2[TS*PADU];   // S_bar bf16 (transposed access)
  const int b = blockIdx.y;
  int bi, bj; decode_pair(blockIdx.x, bi, bj);
  const bool diag = (bi == bj);
  const int ibase = bi*TS, jbase = bj*TS;
  const int tid = threadIdx.x, cg = tid & 15, rr = tid >> 4, c4 = cg*4;
  const size_t bb = (size_t)b * L * L;
  const float sv = pbuf[2*STEPS];

  #pragma unroll
  for (int it = 0; it < 4; ++it){
    int row = it*16 + rr;
    float4 v = ld4(scores + bb + (size_t)(jbase+row)*L + ibase + c4);
    float* d = &buf1[row*PADF + c4];
    d[0]=v.x; d[1]=v.y; d[2]=v.z; d[3]=v.w;
  }
  __syncthreads();

  #pragma unroll
  for (int it = 0; it < 4; ++it){
    int ii = it*16 + rr;
    size_t off = bb + (size_t)(ibase+ii)*L + jbase + c4;
    float4 s4 = ld4(scores + off);
    float4 m4 = ld4(Mm + off);
    float sc[4] = {s4.x,s4.y,s4.z,s4.w};
    float m [4] = {m4.x,m4.y,m4.z,m4.w};
    unsigned short qs[4], qm[4];
    float part = 0.f;
    #pragma unroll
    for (int k = 0; k < 4; ++k){
      float scT = buf1[(c4+k)*PADF + ii];
      float sbv = 0.5f*(sc[k] + scT) - sv;
      unsigned short q = f2bf(sbv);
      buf2[ii*PADU + c4 + k] = q;
      part += (bf2f(q) + sv) * m[k];
      qs[k] = q; qm[k] = f2bf(m[k]);
    }
    us4 so = {qs[0],qs[1],qs[2],qs[3]};
    *(us4*)(Sb + off) = so;
    if constexpr (PACKM){ us4 mo = {qm[0],qm[1],qm[2],qm[3]}; *(us4*)(Mb + off) = mo; }
    part = red16(part);
    if (cg == 0) rsOut[((size_t)b*NT + bj)*L + ibase + ii] = part;
  }
  __syncthreads();

  if (!diag){
    #pragma unroll
    for (int it = 0; it < 4; ++it){
      int jj = it*16 + rr;
      size_t off = bb + (size_t)(jbase+jj)*L + ibase + c4;
      float4 m4 = ld4(Mm + off);
      float m[4] = {m4.x,m4.y,m4.z,m4.w};
      unsigned short qs[4], qm[4];
      float part = 0.f;
      #pragma unroll
      for (int k = 0; k < 4; ++k){
        unsigned short q = buf2[(c4+k)*PADU + jj];   // S_bar symmetric
        part += (bf2f(q) + sv) * m[k];
        qs[k] = q; qm[k] = f2bf(m[k]);
      }
      us4 so = {qs[0],qs[1],qs[2],qs[3]};
      *(us4*)(Sb + off) = so;
      if constexpr (PACKM){ us4 mo = {qm[0],qm[1],qm[2],qm[3]}; *(us4*)(Mb + off) = mo; }
      part = red16(part);
      if (cg == 0) rsOut[((size_t)b*NT + bi)*L + jbase + jj] = part;
    }
  }
}

// one step. FIRST: h from scores, Lm init. LAST: write A=0.5(Hn+HnT)*M_f32,
// no rowsum/Lm outputs, f32 transpose buffers.
template<bool PACKM, bool FIRST, bool LAST>
__global__ __launch_bounds__(256, LAST ? 4 : 7)
void step_kernel(const float* __restrict__ scores,
                 const unsigned short* __restrict__ Sb,
                 const unsigned short* __restrict__ Mb,
                 const float* __restrict__ Mm,
                 const float* __restrict__ rho,
                 float* __restrict__ H,
                 const float* __restrict__ rsIn, float* __restrict__ rsOut,
                 const float* __restrict__ LmIn, float* __restrict__ LmOut,
                 const float* __restrict__ pbuf, const int t)
{
  using BT = typename std::conditional<LAST, float, unsigned short>::type;
  __shared__ BT bufP[TS*PADU];   // Hn_ij (transposed access in B/C)
  __shared__ BT bufQ[TS*PADU];   // Hn_ji (transposed access in C)
  __shared__ float cbuf[2*TS];

  const int b = blockIdx.y;
  int bi, bj; decode_pair(blockIdx.x, bi, bj);
  const bool diag = (bi == bj);
  const int ibase = bi*TS, jbase = bj*TS;
  const int tid = threadIdx.x, cg = tid & 15, rr = tid >> 4, c4 = cg*4;
  const size_t bb = (size_t)b * L * L;
  const float a_t = pbuf[t];

  // ---- c phase ----
  if (tid < 128){
    const int half = tid >> 6, lane = tid & 63;
    const int rowbase = half ? jbase : ibase;
    const float* rp = rsIn + (size_t)b*NT*L + rowbase + lane;
    float rs = 0.f;
    #pragma unroll
    for (int pq = 0; pq < NT; ++pq) rs += rp[(size_t)pq * L];
    const float rowm = rs - 1.0f;
    const float rl = fmaxf(rowm, 0.f);
    float lm;
    if constexpr (FIRST) lm = pbuf[2*STEPS+1] * rl;
    else lm = LmIn[(size_t)b*L + rowbase + lane] + pbuf[STEPS + t - 1] * rl;
    const float sg = (rowm > 0.f) ? 1.f : ((rowm < 0.f) ? -1.f : 0.f);
    cbuf[tid] = lm * sg;
    if constexpr (!LAST){ if (half == 0) LmOut[(size_t)b*L + rowbase + lane] = lm; }
  }
  __syncthreads();

  float mR[4][4], hnR[4][4], part1[4];

  // ---- phase A: tile-ij update ----
  #pragma unroll
  for (int it = 0; it < 4; ++it){
    const int ii = it*16 + rr;
    const size_t offr = (size_t)(ibase+ii)*L + jbase + c4;
    const size_t off = bb + offr;
    float4 h4 = FIRST ? ld4(scores + off) : ld4(H + off);
    float h[4] = {h4.x,h4.y,h4.z,h4.w};
    float m[4];
    if constexpr (LAST){
      float4 m4 = ld4(Mm + off); m[0]=m4.x;m[1]=m4.y;m[2]=m4.z;m[3]=m4.w;
    } else if constexpr (PACKM){
      us4 mu = *(const us4*)(Mb + off);
      m[0]=bf2f(mu.x); m[1]=bf2f(mu.y); m[2]=bf2f(mu.z); m[3]=bf2f(mu.w);
    } else {
      float4 m4 = ld4(Mm + off); m[0]=m4.x;m[1]=m4.y;m[2]=m4.z;m[3]=m4.w;
    }
    us4 su = *(const us4*)(Sb + off);
    float sb[4] = {bf2f(su.x),bf2f(su.y),bf2f(su.z),bf2f(su.w)};
    float4 r4 = ld4(rho + offr);
    float rh[4] = {r4.x,r4.y,r4.z,r4.w};
    const float ci = cbuf[ii];
    float p1 = 0.f, hn[4];
    #pragma unroll
    for (int k = 0; k < 4; ++k){
      const float g = sb[k] - ci - cbuf[TS + c4 + k];
      float x = fmaf(a_t * h[k] * m[k], g, h[k]);
      x = fminf(fmaxf(fabsf(x) - rh[k]*a_t, 0.f), 1.f);
      hn[k] = x; hnR[it][k] = x; mR[it][k] = m[k];
      if constexpr (LAST) bufP[ii*PADU + c4 + k] = x;
      else { bufP[ii*PADU + c4 + k] = f2bf(x); p1 += 0.5f * x * m[k]; }
    }
    if constexpr (!LAST){
      part1[it] = p1;
      float4 o; o.x=hn[0]; o.y=hn[1]; o.z=hn[2]; o.w=hn[3];
      *(float4*)(H + off) = o;
    }
  }
  __syncthreads();

  // ---- phase B: tile-ji update ----
  if (!diag){
    #pragma unroll
    for (int it = 0; it < 4; ++it){
      const int jj = it*16 + rr;
      const size_t offr = (size_t)(jbase+jj)*L + ibase + c4;
      const size_t off = bb + offr;
      float4 h4 = FIRST ? ld4(scores + off) : ld4(H + off);
      float h[4] = {h4.x,h4.y,h4.z,h4.w};
      float m[4];
      if constexpr (LAST){
        float4 m4 = ld4(Mm + off); m[0]=m4.x;m[1]=m4.y;m[2]=m4.z;m[3]=m4.w;
      } else if constexpr (PACKM){
        us4 mu = *(const us4*)(Mb + off);
        m[0]=bf2f(mu.x); m[1]=bf2f(mu.y); m[2]=bf2f(mu.z); m[3]=bf2f(mu.w);
      } else {
        float4 m4 = ld4(Mm + off); m[0]=m4.x;m[1]=m4.y;m[2]=m4.z;m[3]=m4.w;
      }
      us4 su = *(const us4*)(Sb + off);
      float sb[4] = {bf2f(su.x),bf2f(su.y),bf2f(su.z),bf2f(su.w)};
      float4 r4 = ld4(rho + offr);
      float rh[4] = {r4.x,r4.y,r4.z,r4.w};
      const float cj = cbuf[TS + jj];
      float part = 0.f, outv[4];
      #pragma unroll
      for (int k = 0; k < 4; ++k){
        const float g = sb[k] - cj - cbuf[c4 + k];
        float x = fmaf(a_t * h[k] * m[k], g, h[k]);
        x = fminf(fmaxf(fabsf(x) - rh[k]*a_t, 0.f), 1.f);
        float hT;
        if constexpr (LAST) hT = bufP[(c4+k)*PADU + jj];
        else hT = bf2f(bufP[(c4+k)*PADU + jj]);
        if constexpr (LAST){
          outv[k] = 0.5f*(x + hT)*m[k];
          bufQ[jj*PADU + c4 + k] = x;
        } else {
          part += 0.5f*(x + hT)*m[k];
          outv[k] = x;
          bufQ[jj*PADU + c4 + k] = f2bf(x);
        }
      }
      float4 o; o.x=outv[0]; o.y=outv[1]; o.z=outv[2]; o.w=outv[3];
      *(float4*)(H + off) = o;
      if constexpr (!LAST){
        part = red16(part);
        if (cg == 0) rsOut[((size_t)b*NT + bi)*L + jbase + jj] = part;
      }
    }
  }
  __syncthreads();

  // ---- phase C: rows-i (partials or final A_ij) ----
  const BT* hs = diag ? bufP : bufQ;
  #pragma unroll
  for (int it = 0; it < 4; ++it){
    const int ii = it*16 + rr;
    if constexpr (LAST){
      float av[4];
      #pragma unroll
      for (int k = 0; k < 4; ++k){
        float hT = hs[(c4+k)*PADU + ii];
        av[k] = 0.5f*(hnR[it][k] + hT)*mR[it][k];
      }
      size_t off = bb + (size_t)(ibase+ii)*L + jbase + c4;
      float4 o; o.x=av[0]; o.y=av[1]; o.z=av[2]; o.w=av[3];
      *(float4*)(H + off) = o;
    } else {
      float part = part1[it];
      #pragma unroll
      for (int k = 0; k < 4; ++k)
        part += 0.5f * bf2f(hs[(c4+k)*PADU + ii]) * mR[it][k];
      part = red16(part);
      if (cg == 0) rsOut[((size_t)b*NT + bj)*L + ibase + ii] = part;
    }
  }
}

extern "C" void kernel_launch(void* const* d_in, const int* in_sizes, int n_in,
                              void* d_out, int out_size, void* d_ws, size_t ws_size,
                              hipStream_t stream) {
  const float* scores = (const float*)d_in[0];
  const float* Mm     = (const float*)d_in[1];
  const float* rho    = (const float*)d_in[2];
  const float* s      = (const float*)d_in[3];
  const float* w      = (const float*)d_in[4];
  const float* alpha  = (const float*)d_in[5];
  const float* belt   = (const float*)d_in[6];
  const float* lra    = (const float*)d_in[7];
  const float* lrb    = (const float*)d_in[8];
  float* H = (float*)d_out;

  const size_t SBB = (size_t)BATCH*L*L*2;   // bf16 S_bar
  const size_t MBB = (size_t)BATCH*L*L*2;   // bf16 M
  const size_t RSB = (size_t)BATCH*NT*L*4;
  const size_t LMB = (size_t)BATCH*L*4;
  char* wp = (char*)d_ws;
  size_t off = 0;
  unsigned short* Sb = (unsigned short*)wp; off += SBB;
  const bool packm = ws_size >= SBB + MBB + 2*RSB + 2*LMB + 1024;
  unsigned short* Mb = Sb;
  if (packm){ Mb = (unsigned short*)(wp + off); off += MBB; }
  float* rs0  = (float*)(wp + off); off += RSB;
  float* rs1  = (float*)(wp + off); off += RSB;
  float* lm0  = (float*)(wp + off); off += LMB;
  float* lm1  = (float*)(wp + off); off += LMB;
  float* pbuf = (float*)(wp + off);

  params_kernel<<<1, 64, 0, stream>>>(pbuf, s, w, alpha, belt, lra, lrb);

  dim3 grid(NPAIRS, BATCH);
  float* rs[2]  = {rs0, rs1};
  float* lmv[2] = {lm0, lm1};

  if (packm){
    prep_kernel<true><<<grid, 256, 0, stream>>>(scores, Mm, Sb, Mb, rs0, pbuf);
    for (int t = 0; t < STEPS; ++t){
      float* rin = rs[t & 1]; float* rout = rs[(t + 1) & 1];
      const float* lin = lmv[(t + 1) & 1]; float* lout = lmv[t & 1];
      if (t == 0)
        step_kernel<true,true ,false><<<grid,256,0,stream>>>(scores,Sb,Mb,Mm,rho,H,rin,rout,lin,lout,pbuf,t);
      else if (t == STEPS-1)
        step_kernel<true,false,true ><<<grid,256,0,stream>>>(scores,Sb,Mb,Mm,rho,H,rin,rout,lin,lout,pbuf,t);
      else
        step_kernel<true,false,false><<<grid,256,0,stream>>>(scores,Sb,Mb,Mm,rho,H,rin,rout,lin,lout,pbuf,t);
    }
  } else {
    prep_kernel<false><<<grid, 256, 0, stream>>>(scores, Mm, Sb, Mb, rs0, pbuf);
    for (int t = 0; t < STEPS; ++t){
      float* rin = rs[t & 1]; float* rout = rs[(t + 1) & 1];
      const float* lin = lmv[(t + 1) & 1]; float* lout = lmv[t & 1];
      if (t == 0)
        step_kernel<false,true ,false><<<grid,256,0,stream>>>(scores,Sb,Mb,Mm,rho,H,rin,rout,lin,lout,pbuf,t);
      else if (t == STEPS-1)
        step_kernel<false,false,true ><<<grid,256,0,stream>>>(scores,Sb,Mb,Mm,rho,H,rin,rout,lin,lout,pbuf,t);
      else
        step_kernel<false,false,false><<<grid,256,0,stream>>>(scores,Sb,Mb,Mm,rho,H,rin,rout,lin,lout,pbuf,t);
    }
  }
}

// Round 4
// 1258.858 us; speedup vs baseline: 1.6927x; 1.3220x over previous
//
#include <hip/hip_runtime.h>
#include <hip/hip_fp16.h>
#include <math.h>
#include <type_traits>

#define L 1024
#define BATCH 32
#define TS 64
#define PADF 65
#define PADU 66
#define NT 16
#define NPAIRS 136
#define STEPS 20

struct __align__(8) us4 { unsigned short x, y, z, w; };

__device__ __forceinline__ float4 ld4(const float* p){ return *(const float4*)p; }
__device__ __forceinline__ unsigned short f2bf(float x){
  unsigned int u = __float_as_uint(x);
  u += 0x7fffu + ((u >> 16) & 1u);
  return (unsigned short)(u >> 16);
}
__device__ __forceinline__ float bf2f(unsigned short b){
  return __uint_as_float(((unsigned int)b) << 16);
}
__device__ __forceinline__ unsigned short f2h(float x){
  __half h = __float2half(x);
  return *(unsigned short*)&h;
}
__device__ __forceinline__ float h2f(unsigned short u){
  __half h; *(unsigned short*)&h = u;
  return __half2float(h);
}
template<bool H16> __device__ __forceinline__ float dec16(unsigned short u){
  if constexpr (H16) return h2f(u); else return bf2f(u);
}
__device__ __forceinline__ float red16(float v){
  v += __shfl_xor(v, 1); v += __shfl_xor(v, 2);
  v += __shfl_xor(v, 4); v += __shfl_xor(v, 8);
  return v;
}
__device__ __forceinline__ void decode_pair(int p, int& bi, int& bj){
  bi = 0;
  while (p >= NT - bi){ p -= NT - bi; ++bi; }
  bj = bi + p;
}

// pbuf: [0..19] a_t, [20..39] belt*lr_belt^t, [40] s, [41] w
__global__ void params_kernel(float* pbuf, const float* s, const float* w,
                              const float* alpha, const float* belt,
                              const float* lra, const float* lrb) {
  int t = threadIdx.x;
  if (t < STEPS) {
    pbuf[t]         = alpha[0] * powf(lra[0], (float)t);
    pbuf[STEPS + t] = belt[0]  * powf(lrb[0], (float)t);
  }
  if (t == 0) { pbuf[2*STEPS] = s[0]; pbuf[2*STEPS + 1] = w[0]; }
}

// prep: S_bar = 0.5(sc+scT)-s -> bf16 Sb; optional bf16 Mb; rowsum partials of A0.
template<bool PACKM>
__global__ __launch_bounds__(256, 6)
void prep_kernel(const float* __restrict__ scores, const float* __restrict__ Mm,
                 unsigned short* __restrict__ Sb, unsigned short* __restrict__ Mb,
                 float* __restrict__ rsOut, const float* __restrict__ pbuf)
{
  __shared__ float buf1[TS*PADF];
  __shared__ unsigned short buf2[TS*PADU];
  const int b = blockIdx.y;
  int bi, bj; decode_pair(blockIdx.x, bi, bj);
  const bool diag = (bi == bj);
  const int ibase = bi*TS, jbase = bj*TS;
  const int tid = threadIdx.x, cg = tid & 15, rr = tid >> 4, c4 = cg*4;
  const size_t bb = (size_t)b * L * L;
  const float sv = pbuf[2*STEPS];

  #pragma unroll
  for (int it = 0; it < 4; ++it){
    int row = it*16 + rr;
    float4 v = ld4(scores + bb + (size_t)(jbase+row)*L + ibase + c4);
    float* d = &buf1[row*PADF + c4];
    d[0]=v.x; d[1]=v.y; d[2]=v.z; d[3]=v.w;
  }
  __syncthreads();

  #pragma unroll
  for (int it = 0; it < 4; ++it){
    int ii = it*16 + rr;
    size_t off = bb + (size_t)(ibase+ii)*L + jbase + c4;
    float4 s4 = ld4(scores + off);
    float4 m4 = ld4(Mm + off);
    float sc[4] = {s4.x,s4.y,s4.z,s4.w};
    float m [4] = {m4.x,m4.y,m4.z,m4.w};
    unsigned short qs[4], qm[4];
    float part = 0.f;
    #pragma unroll
    for (int k = 0; k < 4; ++k){
      float scT = buf1[(c4+k)*PADF + ii];
      float sbv = 0.5f*(sc[k] + scT) - sv;
      unsigned short q = f2bf(sbv);
      buf2[ii*PADU + c4 + k] = q;
      part += (bf2f(q) + sv) * m[k];
      qs[k] = q; qm[k] = f2bf(m[k]);
    }
    us4 so = {qs[0],qs[1],qs[2],qs[3]};
    *(us4*)(Sb + off) = so;
    if constexpr (PACKM){ us4 mo = {qm[0],qm[1],qm[2],qm[3]}; *(us4*)(Mb + off) = mo; }
    part = red16(part);
    if (cg == 0) rsOut[((size_t)b*NT + bj)*L + ibase + ii] = part;
  }
  __syncthreads();

  if (!diag){
    #pragma unroll
    for (int it = 0; it < 4; ++it){
      int jj = it*16 + rr;
      size_t off = bb + (size_t)(jbase+jj)*L + ibase + c4;
      float4 m4 = ld4(Mm + off);
      float m[4] = {m4.x,m4.y,m4.z,m4.w};
      unsigned short qs[4], qm[4];
      float part = 0.f;
      #pragma unroll
      for (int k = 0; k < 4; ++k){
        unsigned short q = buf2[(c4+k)*PADU + jj];
        part += (bf2f(q) + sv) * m[k];
        qs[k] = q; qm[k] = f2bf(m[k]);
      }
      us4 so = {qs[0],qs[1],qs[2],qs[3]};
      *(us4*)(Sb + off) = so;
      if constexpr (PACKM){ us4 mo = {qm[0],qm[1],qm[2],qm[3]}; *(us4*)(Mb + off) = mo; }
      part = red16(part);
      if (cg == 0) rsOut[((size_t)b*NT + bi)*L + jbase + jj] = part;
    }
  }
}

// one step. FIRST: h from scores, Lm init. LAST: write A=0.5(Hn+HnT)*M_f32 to Hf.
// H16: state carried as fp16 in Hh; else f32 in Hf.
template<bool PACKM, bool H16, bool FIRST, bool LAST>
__global__ __launch_bounds__(256, LAST ? 4 : 7)
void step_kernel(const float* __restrict__ scores,
                 const unsigned short* __restrict__ Sb,
                 const unsigned short* __restrict__ Mb,
                 const float* __restrict__ Mm,
                 const float* __restrict__ rho,
                 float* __restrict__ Hf,
                 unsigned short* __restrict__ Hh,
                 const float* __restrict__ rsIn, float* __restrict__ rsOut,
                 const float* __restrict__ LmIn, float* __restrict__ LmOut,
                 const float* __restrict__ pbuf, const int t)
{
  using BT = typename std::conditional<LAST, float, unsigned short>::type;
  __shared__ BT bufP[TS*PADU];   // Hn_ij
  __shared__ BT bufQ[TS*PADU];   // Hn_ji
  __shared__ float cbuf[2*TS];

  const int b = blockIdx.y;
  int bi, bj; decode_pair(blockIdx.x, bi, bj);
  const bool diag = (bi == bj);
  const int ibase = bi*TS, jbase = bj*TS;
  const int tid = threadIdx.x, cg = tid & 15, rr = tid >> 4, c4 = cg*4;
  const size_t bb = (size_t)b * L * L;
  const float a_t = pbuf[t];

  // ---- c phase ----
  if (tid < 128){
    const int half = tid >> 6, lane = tid & 63;
    const int rowbase = half ? jbase : ibase;
    const float* rp = rsIn + (size_t)b*NT*L + rowbase + lane;
    float rs = 0.f;
    #pragma unroll
    for (int pq = 0; pq < NT; ++pq) rs += rp[(size_t)pq * L];
    const float rowm = rs - 1.0f;
    const float rl = fmaxf(rowm, 0.f);
    float lm;
    if constexpr (FIRST) lm = pbuf[2*STEPS+1] * rl;
    else lm = LmIn[(size_t)b*L + rowbase + lane] + pbuf[STEPS + t - 1] * rl;
    const float sg = (rowm > 0.f) ? 1.f : ((rowm < 0.f) ? -1.f : 0.f);
    cbuf[tid] = lm * sg;
    if constexpr (!LAST){ if (half == 0) LmOut[(size_t)b*L + rowbase + lane] = lm; }
  }
  __syncthreads();

  float mR[4][4], hnR[4][4], part1[4];

  // ---- phase A: tile-ij update ----
  #pragma unroll
  for (int it = 0; it < 4; ++it){
    const int ii = it*16 + rr;
    const size_t offr = (size_t)(ibase+ii)*L + jbase + c4;
    const size_t off = bb + offr;
    float h[4];
    if constexpr (FIRST){
      float4 h4 = ld4(scores + off); h[0]=h4.x;h[1]=h4.y;h[2]=h4.z;h[3]=h4.w;
    } else if constexpr (H16){
      us4 hu = *(const us4*)(Hh + off);
      h[0]=h2f(hu.x); h[1]=h2f(hu.y); h[2]=h2f(hu.z); h[3]=h2f(hu.w);
    } else {
      float4 h4 = ld4(Hf + off); h[0]=h4.x;h[1]=h4.y;h[2]=h4.z;h[3]=h4.w;
    }
    float m[4];
    if constexpr (LAST){
      float4 m4 = ld4(Mm + off); m[0]=m4.x;m[1]=m4.y;m[2]=m4.z;m[3]=m4.w;
    } else if constexpr (PACKM){
      us4 mu = *(const us4*)(Mb + off);
      m[0]=bf2f(mu.x); m[1]=bf2f(mu.y); m[2]=bf2f(mu.z); m[3]=bf2f(mu.w);
    } else {
      float4 m4 = ld4(Mm + off); m[0]=m4.x;m[1]=m4.y;m[2]=m4.z;m[3]=m4.w;
    }
    us4 su = *(const us4*)(Sb + off);
    float sb[4] = {bf2f(su.x),bf2f(su.y),bf2f(su.z),bf2f(su.w)};
    float4 r4 = ld4(rho + offr);
    float rh[4] = {r4.x,r4.y,r4.z,r4.w};
    const float ci = cbuf[ii];
    float p1 = 0.f;
    unsigned short hb[4];
    float hn[4];
    #pragma unroll
    for (int k = 0; k < 4; ++k){
      const float g = sb[k] - ci - cbuf[TS + c4 + k];
      float x = fmaf(a_t * h[k] * m[k], g, h[k]);
      x = fminf(fmaxf(fabsf(x) - rh[k]*a_t, 0.f), 1.f);
      mR[it][k] = m[k];
      if constexpr (LAST){
        hnR[it][k] = x;
        bufP[ii*PADU + c4 + k] = x;
      } else if constexpr (H16){
        unsigned short bits = f2h(x);
        float xq = h2f(bits);
        hb[k] = bits;
        bufP[ii*PADU + c4 + k] = bits;
        p1 += 0.5f * xq * m[k];
      } else {
        hn[k] = x;
        bufP[ii*PADU + c4 + k] = f2bf(x);
        p1 += 0.5f * x * m[k];
      }
    }
    if constexpr (!LAST){
      part1[it] = p1;
      if constexpr (H16){
        us4 o = {hb[0],hb[1],hb[2],hb[3]};
        *(us4*)(Hh + off) = o;
      } else {
        float4 o; o.x=hn[0]; o.y=hn[1]; o.z=hn[2]; o.w=hn[3];
        *(float4*)(Hf + off) = o;
      }
    }
  }
  __syncthreads();

  // ---- phase B: tile-ji update ----
  if (!diag){
    #pragma unroll
    for (int it = 0; it < 4; ++it){
      const int jj = it*16 + rr;
      const size_t offr = (size_t)(jbase+jj)*L + ibase + c4;
      const size_t off = bb + offr;
      float h[4];
      if constexpr (FIRST){
        float4 h4 = ld4(scores + off); h[0]=h4.x;h[1]=h4.y;h[2]=h4.z;h[3]=h4.w;
      } else if constexpr (H16){
        us4 hu = *(const us4*)(Hh + off);
        h[0]=h2f(hu.x); h[1]=h2f(hu.y); h[2]=h2f(hu.z); h[3]=h2f(hu.w);
      } else {
        float4 h4 = ld4(Hf + off); h[0]=h4.x;h[1]=h4.y;h[2]=h4.z;h[3]=h4.w;
      }
      float m[4];
      if constexpr (LAST){
        float4 m4 = ld4(Mm + off); m[0]=m4.x;m[1]=m4.y;m[2]=m4.z;m[3]=m4.w;
      } else if constexpr (PACKM){
        us4 mu = *(const us4*)(Mb + off);
        m[0]=bf2f(mu.x); m[1]=bf2f(mu.y); m[2]=bf2f(mu.z); m[3]=bf2f(mu.w);
      } else {
        float4 m4 = ld4(Mm + off); m[0]=m4.x;m[1]=m4.y;m[2]=m4.z;m[3]=m4.w;
      }
      us4 su = *(const us4*)(Sb + off);
      float sb[4] = {bf2f(su.x),bf2f(su.y),bf2f(su.z),bf2f(su.w)};
      float4 r4 = ld4(rho + offr);
      float rh[4] = {r4.x,r4.y,r4.z,r4.w};
      const float cj = cbuf[TS + jj];
      float part = 0.f;
      unsigned short hb[4];
      float outv[4];
      #pragma unroll
      for (int k = 0; k < 4; ++k){
        const float g = sb[k] - cj - cbuf[c4 + k];
        float x = fmaf(a_t * h[k] * m[k], g, h[k]);
        x = fminf(fmaxf(fabsf(x) - rh[k]*a_t, 0.f), 1.f);
        if constexpr (LAST){
          float hT = bufP[(c4+k)*PADU + jj];
          outv[k] = 0.5f*(x + hT)*m[k];
          bufQ[jj*PADU + c4 + k] = x;
        } else if constexpr (H16){
          unsigned short bits = f2h(x);
          float xq = h2f(bits);
          hb[k] = bits;
          float hT = h2f(bufP[(c4+k)*PADU + jj]);
          part += 0.5f*(xq + hT)*m[k];
          bufQ[jj*PADU + c4 + k] = bits;
        } else {
          float hT = bf2f(bufP[(c4+k)*PADU + jj]);
          part += 0.5f*(x + hT)*m[k];
          outv[k] = x;
          bufQ[jj*PADU + c4 + k] = f2bf(x);
        }
      }
      if constexpr (LAST){
        float4 o; o.x=outv[0]; o.y=outv[1]; o.z=outv[2]; o.w=outv[3];
        *(float4*)(Hf + off) = o;
      } else if constexpr (H16){
        us4 o = {hb[0],hb[1],hb[2],hb[3]};
        *(us4*)(Hh + off) = o;
      } else {
        float4 o; o.x=outv[0]; o.y=outv[1]; o.z=outv[2]; o.w=outv[3];
        *(float4*)(Hf + off) = o;
      }
      if constexpr (!LAST){
        part = red16(part);
        if (cg == 0) rsOut[((size_t)b*NT + bi)*L + jbase + jj] = part;
      }
    }
  }
  __syncthreads();

  // ---- phase C: rows-i (partials or final A_ij) ----
  const BT* hs = diag ? bufP : bufQ;
  #pragma unroll
  for (int it = 0; it < 4; ++it){
    const int ii = it*16 + rr;
    if constexpr (LAST){
      float av[4];
      #pragma unroll
      for (int k = 0; k < 4; ++k){
        float hT = hs[(c4+k)*PADU + ii];
        av[k] = 0.5f*(hnR[it][k] + hT)*mR[it][k];
      }
      size_t off = bb + (size_t)(ibase+ii)*L + jbase + c4;
      float4 o; o.x=av[0]; o.y=av[1]; o.z=av[2]; o.w=av[3];
      *(float4*)(Hf + off) = o;
    } else {
      float part = part1[it];
      #pragma unroll
      for (int k = 0; k < 4; ++k)
        part += 0.5f * dec16<H16>(hs[(c4+k)*PADU + ii]) * mR[it][k];
      part = red16(part);
      if (cg == 0) rsOut[((size_t)b*NT + bj)*L + ibase + ii] = part;
    }
  }
}

template<bool PACKM, bool H16>
static void run_steps(const float* scores, const unsigned short* Sb,
                      const unsigned short* Mb, const float* Mm, const float* rho,
                      float* Hf, unsigned short* Hh,
                      float** rs, float** lmv, const float* pbuf, hipStream_t stream)
{
  dim3 grid(NPAIRS, BATCH);
  for (int t = 0; t < STEPS; ++t){
    float* rin = rs[t & 1]; float* rout = rs[(t + 1) & 1];
    const float* lin = lmv[(t + 1) & 1]; float* lout = lmv[t & 1];
    if (t == 0)
      step_kernel<PACKM,H16,true ,false><<<grid,256,0,stream>>>(scores,Sb,Mb,Mm,rho,Hf,Hh,rin,rout,lin,lout,pbuf,t);
    else if (t == STEPS-1)
      step_kernel<PACKM,H16,false,true ><<<grid,256,0,stream>>>(scores,Sb,Mb,Mm,rho,Hf,Hh,rin,rout,lin,lout,pbuf,t);
    else
      step_kernel<PACKM,H16,false,false><<<grid,256,0,stream>>>(scores,Sb,Mb,Mm,rho,Hf,Hh,rin,rout,lin,lout,pbuf,t);
  }
}

extern "C" void kernel_launch(void* const* d_in, const int* in_sizes, int n_in,
                              void* d_out, int out_size, void* d_ws, size_t ws_size,
                              hipStream_t stream) {
  const float* scores = (const float*)d_in[0];
  const float* Mm     = (const float*)d_in[1];
  const float* rho    = (const float*)d_in[2];
  const float* s      = (const float*)d_in[3];
  const float* w      = (const float*)d_in[4];
  const float* alpha  = (const float*)d_in[5];
  const float* belt   = (const float*)d_in[6];
  const float* lra    = (const float*)d_in[7];
  const float* lrb    = (const float*)d_in[8];
  float* Hf = (float*)d_out;

  const size_t SBB = (size_t)BATCH*L*L*2;   // bf16 S_bar
  const size_t MBB = (size_t)BATCH*L*L*2;   // bf16 M
  const size_t HHB = (size_t)BATCH*L*L*2;   // fp16 H state
  const size_t RSB = (size_t)BATCH*NT*L*4;
  const size_t LMB = (size_t)BATCH*L*4;
  const size_t need_base = 2*RSB + 2*LMB + 4096;

  char* wp = (char*)d_ws;
  const bool h16   = ws_size >= SBB + MBB + HHB + need_base;
  const bool packm = h16 || (ws_size >= SBB + MBB + need_base);

  size_t off = 0;
  unsigned short* Sb = (unsigned short*)wp; off += SBB;
  unsigned short* Mb = Sb;
  if (packm){ Mb = (unsigned short*)(wp + off); off += MBB; }
  unsigned short* Hh = nullptr;
  if (h16){ Hh = (unsigned short*)(wp + off); off += HHB; }
  float* rs0  = (float*)(wp + off); off += RSB;
  float* rs1  = (float*)(wp + off); off += RSB;
  float* lm0  = (float*)(wp + off); off += LMB;
  float* lm1  = (float*)(wp + off); off += LMB;
  float* pbuf = (float*)(wp + off);

  params_kernel<<<1, 64, 0, stream>>>(pbuf, s, w, alpha, belt, lra, lrb);

  dim3 grid(NPAIRS, BATCH);
  float* rs[2]  = {rs0, rs1};
  float* lmv[2] = {lm0, lm1};

  if (h16){
    prep_kernel<true><<<grid, 256, 0, stream>>>(scores, Mm, Sb, Mb, rs0, pbuf);
    run_steps<true,true>(scores, Sb, Mb, Mm, rho, Hf, Hh, rs, lmv, pbuf, stream);
  } else if (packm){
    prep_kernel<true><<<grid, 256, 0, stream>>>(scores, Mm, Sb, Mb, rs0, pbuf);
    run_steps<true,false>(scores, Sb, Mb, Mm, rho, Hf, Hh, rs, lmv, pbuf, stream);
  } else {
    prep_kernel<false><<<grid, 256, 0, stream>>>(scores, Mm, Sb, Mb, rs0, pbuf);
    run_steps<false,false>(scores, Sb, Mb, Mm, rho, Hf, Hh, rs, lmv, pbuf, stream);
  }
}